// Round 6
// baseline (685.774 us; speedup 1.0000x reference)
//
#include <hip/hip_runtime.h>
#include <hip/hip_bf16.h>
#include <hip/hip_cooperative_groups.h>

// Problem constants (B=4, C=256, H=W=64, N=4096, G=32, DQK=32)
#define NB 4
#define CD 256
#define NT 4096
#define DQ 32

namespace cg = cooperative_groups;

typedef __attribute__((ext_vector_type(8))) __bf16 bf16x8;
typedef __attribute__((ext_vector_type(16))) float float16v;
typedef __attribute__((ext_vector_type(4))) unsigned int uint4v;
typedef __attribute__((ext_vector_type(2))) unsigned int uint2v;

#if __has_builtin(__builtin_amdgcn_exp2f)
#define EXP2(x) __builtin_amdgcn_exp2f(x)
#else
#define EXP2(x) exp2f(x)
#endif

__device__ inline unsigned short f2bf(float f) {
  unsigned u = __float_as_uint(f);
  u += 0x7fffu + ((u >> 16) & 1u);
  return (unsigned short)(u >> 16);
}

__device__ inline bf16x8 combine_frag(const unsigned short* p0,
                                      const unsigned short* p1, float inv) {
  uint4v ua = *(const uint4v*)p0;
  uint4v ub = *(const uint4v*)p1;
  uint4v r;
#pragma unroll
  for (int j = 0; j < 4; j++) {
    float lo = __uint_as_float(ua[j] << 16) + __uint_as_float(ub[j] << 16);
    float hi = __uint_as_float(ua[j] & 0xffff0000u) +
               __uint_as_float(ub[j] & 0xffff0000u);
    lo *= inv;
    hi *= inv;
    r[j] = __builtin_amdgcn_perm(__float_as_uint(hi), __float_as_uint(lo),
                                 0x07060302u);
  }
  return *(bf16x8*)&r;
}

// ---------------------------------------------------------------------------
// One cooperative mega-kernel: 5 phases separated by grid.sync(). 512 blocks
// x 256 threads; __launch_bounds__(256,2) guarantees >=2 blocks/CU so the
// cooperative launch's co-residency requirement is met with margin (LDS
// 30.7KB -> 5/CU fit). Phase bodies are the R5 kernels verbatim, wrapped in
// grid-stride unit loops. Rationale: total - attn has been ~130us across 5
// rounds regardless of how those kernels were written => per-dispatch
// overhead; fusing removes it.
// ---------------------------------------------------------------------------
__global__ __launch_bounds__(256, 2) void fused_all(
    const float* __restrict__ x, const float* __restrict__ gamma,
    const float* __restrict__ beta, const float* __restrict__ wq,
    const float* __restrict__ bq, const float* __restrict__ wk,
    const float* __restrict__ bk, const float* __restrict__ wv,
    const float* __restrict__ bv, const float* __restrict__ wp,
    const float* __restrict__ bp, float* __restrict__ out,
    char* __restrict__ ws) {
  cg::grid_group grid = cg::this_grid();
  int tid = threadIdx.x;
  int nblk = (int)gridDim.x;  // 512

  // workspace layout (same as R5)
  unsigned short* Pa = (unsigned short*)ws;                  // 8MB (h, then Pa)
  unsigned short* qk = (unsigned short*)(ws + 8388608);      // 2MB
  unsigned short* v = (unsigned short*)(ws + 10485760);      // 8MB
  unsigned short* Pb = (unsigned short*)(ws + 18874368);     // 8MB
  unsigned short* wqkv = (unsigned short*)(ws + 27262976);   // 160KB
  unsigned short* wpb = (unsigned short*)(ws + 27426816);    // 128KB
  float* bias = (float*)(ws + 27557888);                     // 1.25KB
  float* accum = (float*)(ws + 27559168);                    // 4KB
  float* lp4 = (float*)(ws + 27563264);                      // 256KB
  unsigned short* h = Pa;  // h lives until qkv consumes it; attn reuses as Pa

  __shared__ alignas(16) char smem_raw[30720];

  // ========== Phase A: GroupNorm partial stats + weight packing ==========
  for (int u = blockIdx.x; u < 1090; u += nblk) {
    __syncthreads();  // protect smem reuse across units
    if (u < 512) {
      int bg = u >> 2, ch = u & 3;
      const float4* xp = (const float4*)(x + (size_t)bg * 32768 + ch * 8192);
      float s = 0.f, ss = 0.f;
#pragma unroll
      for (int i = 0; i < 8; i++) {
        float4 vv = xp[tid + 256 * i];
        s += vv.x + vv.y + vv.z + vv.w;
        ss += vv.x * vv.x + vv.y * vv.y + vv.z * vv.z + vv.w * vv.w;
      }
      int wid = tid >> 6, lane = tid & 63;
#pragma unroll
      for (int off = 32; off >= 1; off >>= 1) {
        s += __shfl_xor(s, off);
        ss += __shfl_xor(ss, off);
      }
      float* red = (float*)smem_raw;
      if (lane == 0) { red[wid] = s; red[4 + wid] = ss; }
      __syncthreads();
      if (tid == 0) {
        accum[2 * u] = red[0] + red[1] + red[2] + red[3];
        accum[2 * u + 1] = red[4] + red[5] + red[6] + red[7];
      }
    } else {
      const float scale2 = 0.2550348909867343f;  // log2(e)/sqrt(32)
      int i = (u - 512) * 256 + tid;
      if (i < 320 * 256) {
        int j = i >> 8, c = i & 255;
        float vv;
        if (j < 32) vv = wq[j * 256 + c] * scale2;
        else if (j < 64) vv = wk[(j - 32) * 256 + c];
        else vv = wv[(j - 64) * 256 + c];
        wqkv[i] = f2bf(vv);
      } else if (i < 320 * 256 + 256 * 256) {
        int k = i - 320 * 256;
        wpb[k] = f2bf(wp[k]);
      } else if (i < 320 * 256 + 256 * 256 + 320) {
        int j = i - (320 * 256 + 256 * 256);
        float vv;
        if (j < 32) vv = bq[j] * scale2;
        else if (j < 64) vv = bk[j - 32];
        else vv = bv[j - 64];
        bias[j] = vv;
      }
    }
  }
  grid.sync();

  // ========== Phase B: GroupNorm apply -> h[B][N][C] bf16 ==========
  for (int u = blockIdx.x; u < 512; u += nblk) {
    int bg = u >> 2, nc = u & 3;
    float S = accum[8 * bg] + accum[8 * bg + 2] + accum[8 * bg + 4] +
              accum[8 * bg + 6];
    float SS = accum[8 * bg + 1] + accum[8 * bg + 3] + accum[8 * bg + 5] +
               accum[8 * bg + 7];
    float mu = S * (1.f / 32768.f);
    float var = SS * (1.f / 32768.f) - mu * mu;
    float rstd = rsqrtf(var + 1e-5f);
    int b = bg >> 5, g = bg & 31, c0 = g * 8;
    float gam[8], bet[8];
#pragma unroll
    for (int j = 0; j < 8; j++) {
      gam[j] = gamma[c0 + j];
      bet[j] = beta[c0 + j];
    }
    const float* xb = x + (size_t)bg * 32768;
#pragma unroll
    for (int i = 0; i < 4; i++) {
      int n = nc * 1024 + tid + 256 * i;
      unsigned short hv[8];
#pragma unroll
      for (int j = 0; j < 8; j++) {
        float y = (xb[j * NT + n] - mu) * rstd * gam[j] + bet[j];
        hv[j] = f2bf(y);
      }
      *(uint4v*)(h + ((size_t)(b * NT + n) * CD + c0)) = *(uint4v*)hv;
    }
  }
  grid.sync();

  // ========== Phase C: QKV GEMM (zero-LDS, 32x32x16 MFMA) ==========
  for (int u = blockIdx.x; u < 640; u += nblk) {
    int b = u / 160;
    int rem = u - 160 * b;
    int mt = rem >> 5, nt = rem & 31;
    int lane = tid & 63;
    int w = tid >> 6, mi = w & 1, ni = w >> 1;
    int l31 = lane & 31, hh = lane >> 5;
    int m_base = mt * 64 + 32 * mi;
    int n_base = nt * 128 + 64 * ni;
    const unsigned short* Arow = wqkv + (size_t)(m_base + l31) * 256 + 8 * hh;
    const unsigned short* Hb = h + (size_t)b * NT * CD;
    const unsigned short* h0 = Hb + (size_t)(n_base + l31) * CD + 8 * hh;
    const unsigned short* h1 = h0 + (size_t)32 * CD;
    float16v acc0, acc1;
#pragma unroll
    for (int r = 0; r < 16; r++) { acc0[r] = 0.f; acc1[r] = 0.f; }
#pragma unroll
    for (int s = 0; s < 16; s++) {
      bf16x8 af = *(const bf16x8*)(Arow + 16 * s);
      bf16x8 b0 = *(const bf16x8*)(h0 + 16 * s);
      bf16x8 b1 = *(const bf16x8*)(h1 + 16 * s);
      acc0 = __builtin_amdgcn_mfma_f32_32x32x16_bf16(af, b0, acc0, 0, 0, 0);
      acc1 = __builtin_amdgcn_mfma_f32_32x32x16_bf16(af, b1, acc1, 0, 0, 0);
    }
    float bj[16];
    int jr[16];
#pragma unroll
    for (int r = 0; r < 16; r++) {
      jr[r] = m_base + (r & 3) + 8 * (r >> 2) + 4 * hh;
      bj[r] = bias[jr[r]];
    }
#pragma unroll
    for (int half = 0; half < 2; half++) {
      int n = n_base + 32 * half + l31;
#pragma unroll
      for (int r = 0; r < 16; r++) {
        float val = (half ? acc1[r] : acc0[r]) + bj[r];
        int j = jr[r];
        if (j < 64) {
          qk[((size_t)b * NT + n) * 64 + j] = f2bf(val);
        } else {
          v[((size_t)b * CD + (j - 64)) * NT + n] = f2bf(val);
        }
      }
    }
  }
  grid.sync();

  // ========== Phase D: fused attention (key-split x2, partials) ==========
  {
    unsigned short* Ks = (unsigned short*)smem_raw;  // 64*36 shorts (4608 B)
    unsigned short* Vs = Ks + 64 * 36;               // 128*68 shorts (17408 B)
    unsigned short* Pbuf = Vs + 128 * 68;            // 2*32*68 shorts (8704 B)
    for (int u = blockIdx.x; u < 1024; u += nblk) {
      int bx = u & 127;
      int E0 = ((u >> 7) & 1) * 128;
      int b = u >> 8;
      int n0 = (bx >> 1) * 64;
      int kh = bx & 1;
      int lane = tid & 63, w = tid >> 6;
      int qi = w & 1, ei = w >> 1;
      int l31 = lane & 31, hh = lane >> 5;

      const unsigned short* qkb = qk + (size_t)b * NT * 64;
      const unsigned short* Vb = v + (size_t)b * CD * NT;

      int n_g = n0 + 32 * qi + l31;
      bf16x8 qfr[2];
      qfr[0] = *(const bf16x8*)&qkb[(size_t)n_g * 64 + 8 * hh];
      qfr[1] = *(const bf16x8*)&qkb[(size_t)n_g * 64 + 8 * hh + 16];

      int se = tid >> 1, smh = (tid & 1) * 32;
      int skr = tid >> 2, skc = (tid & 3) * 8;

      int mbase = kh * 2048;
      uint4v vreg[4];
      uint4v kreg;
      {
        const unsigned short* vp = &Vb[(size_t)(E0 + se) * NT + mbase + smh];
#pragma unroll
        for (int uu = 0; uu < 4; uu++) vreg[uu] = *(const uint4v*)(vp + 8 * uu);
        kreg = *(const uint4v*)&qkb[(size_t)(mbase + skr) * 64 + 32 + skc];
      }

      float16v acc[2];
#pragma unroll
      for (int et = 0; et < 2; et++)
#pragma unroll
        for (int r = 0; r < 16; r++) acc[et][r] = 0.f;
      float lsum = 0.f;
      unsigned short* Prow = &Pbuf[(qi * 32 + l31) * 68];

      __syncthreads();  // protect smem reuse across units
      for (int it = 0; it < 32; it++) {
        *(uint4v*)&Ks[skr * 36 + skc] = kreg;
        if (it + 1 < 32) {
          int m1 = mbase + (it + 1) * 64;
          kreg = *(const uint4v*)&qkb[(size_t)(m1 + skr) * 64 + 32 + skc];
        }
        __syncthreads();  // barrier1: Ks ready; prior reads done

#pragma unroll
        for (int uu = 0; uu < 4; uu++)
          *(uint4v*)&Vs[se * 68 + smh + 8 * uu] = vreg[uu];
        if (it + 1 < 32) {
          int m1 = mbase + (it + 1) * 64;
          const unsigned short* vp = &Vb[(size_t)(E0 + se) * NT + m1 + smh];
#pragma unroll
          for (int uu = 0; uu < 4; uu++)
            vreg[uu] = *(const uint4v*)(vp + 8 * uu);
        }

        float16v st;
#pragma unroll
        for (int r = 0; r < 16; r++) st[r] = 0.f;
#pragma unroll
        for (int s = 0; s < 2; s++) {
          bf16x8 af =
              *(const bf16x8*)&Ks[(32 * ei + l31) * 36 + 16 * s + 8 * hh];
          st = __builtin_amdgcn_mfma_f32_32x32x16_bf16(af, qfr[s], st, 0, 0, 0);
        }
#pragma unroll
        for (int rq = 0; rq < 4; rq++) {
          float e0 = EXP2(st[4 * rq + 0]);
          float e1 = EXP2(st[4 * rq + 1]);
          float e2 = EXP2(st[4 * rq + 2]);
          float e3 = EXP2(st[4 * rq + 3]);
          lsum += (e0 + e1) + (e2 + e3);
          uint2v pw;
          pw[0] = __builtin_amdgcn_perm(__float_as_uint(e1),
                                        __float_as_uint(e0), 0x07060302u);
          pw[1] = __builtin_amdgcn_perm(__float_as_uint(e3),
                                        __float_as_uint(e2), 0x07060302u);
          *(uint2v*)&Prow[8 * rq + 4 * hh + 32 * ei] = pw;
        }
        __syncthreads();  // barrier2: P + Vs ready

#pragma unroll
        for (int sp = 0; sp < 4; sp++) {
          bf16x8 afr =
              *(const bf16x8*)&Pbuf[(qi * 32 + l31) * 68 + 16 * sp + 8 * hh];
#pragma unroll
          for (int et = 0; et < 2; et++) {
            bf16x8 bfr = *(const bf16x8*)&Vs[(64 * ei + 32 * et + l31) * 68 +
                                             16 * sp + 8 * hh];
            acc[et] = __builtin_amdgcn_mfma_f32_32x32x16_bf16(afr, bfr, acc[et],
                                                              0, 0, 0);
          }
        }
      }

      lsum += __shfl_xor(lsum, 32);
      unsigned short* Pout = (kh ? Pb : Pa) + (size_t)b * NT * CD;
#pragma unroll
      for (int r = 0; r < 16; r++) {
        int nl = (r & 3) + 8 * (r >> 2) + 4 * hh;
        size_t row = (size_t)(n0 + 32 * qi + nl) * CD + E0 + 64 * ei + l31;
#pragma unroll
        for (int et = 0; et < 2; et++) {
          Pout[row + 32 * et] = f2bf(acc[et][r]);
        }
      }
      if (hh == 0) {
        lp4[(size_t)((kh * 2 + ei) * NB + b) * NT + n0 + 32 * qi + l31] = lsum;
      }
    }
  }
  grid.sync();

  // ========== Phase E: proj GEMM + combine + bias + residual ==========
  for (int u = blockIdx.x; u < 512; u += nblk) {
    int nt = u & 31, mt = (u >> 5) & 3, b = u >> 7;
    int lane = tid & 63;
    int w = tid >> 6, mi = w & 1, ni = w >> 1;
    int l31 = lane & 31, hh = lane >> 5;
    int m_base = mt * 64 + 32 * mi;
    int n_base = nt * 128 + 64 * ni;
    const unsigned short* Arow = wpb + (size_t)(m_base + l31) * 256 + 8 * hh;
    int nA = n_base + l31, nB = nA + 32;
    float lA = 0.f, lB = 0.f;
#pragma unroll
    for (int s4 = 0; s4 < 4; s4++) {
      lA += lp4[(size_t)(s4 * NB + b) * NT + nA];
      lB += lp4[(size_t)(s4 * NB + b) * NT + nB];
    }
    float invA = 1.f / lA, invB = 1.f / lB;
    const unsigned short* a0 = Pa + ((size_t)b * NT + nA) * CD + 8 * hh;
    const unsigned short* a1 = Pa + ((size_t)b * NT + nB) * CD + 8 * hh;
    const unsigned short* c0 = Pb + ((size_t)b * NT + nA) * CD + 8 * hh;
    const unsigned short* c1 = Pb + ((size_t)b * NT + nB) * CD + 8 * hh;
    float16v acc0, acc1;
#pragma unroll
    for (int r = 0; r < 16; r++) { acc0[r] = 0.f; acc1[r] = 0.f; }
#pragma unroll
    for (int s = 0; s < 16; s++) {
      bf16x8 af = *(const bf16x8*)(Arow + 16 * s);
      bf16x8 b0 = combine_frag(a0 + 16 * s, c0 + 16 * s, invA);
      bf16x8 b1 = combine_frag(a1 + 16 * s, c1 + 16 * s, invB);
      acc0 = __builtin_amdgcn_mfma_f32_32x32x16_bf16(af, b0, acc0, 0, 0, 0);
      acc1 = __builtin_amdgcn_mfma_f32_32x32x16_bf16(af, b1, acc1, 0, 0, 0);
    }
#pragma unroll
    for (int half = 0; half < 2; half++) {
      int n = n_base + 32 * half + l31;
#pragma unroll
      for (int r = 0; r < 16; r++) {
        int f = m_base + (r & 3) + 8 * (r >> 2) + 4 * hh;
        size_t idx = ((size_t)b * CD + f) * NT + n;
        out[idx] = x[idx] + (half ? acc1[r] : acc0[r]) + bp[f];
      }
    }
  }
}

extern "C" void kernel_launch(void* const* d_in, const int* in_sizes, int n_in,
                              void* d_out, int out_size, void* d_ws,
                              size_t ws_size, hipStream_t stream) {
  (void)in_sizes; (void)n_in; (void)out_size; (void)ws_size;
  const float* x = (const float*)d_in[0];
  const float* gamma = (const float*)d_in[1];
  const float* beta = (const float*)d_in[2];
  const float* wq = (const float*)d_in[3];
  const float* bq = (const float*)d_in[4];
  const float* wk = (const float*)d_in[5];
  const float* bk = (const float*)d_in[6];
  const float* wv = (const float*)d_in[7];
  const float* bv = (const float*)d_in[8];
  const float* wp = (const float*)d_in[9];
  const float* bp = (const float*)d_in[10];
  float* out = (float*)d_out;
  char* ws = (char*)d_ws;

  void* args[] = {(void*)&x,  (void*)&gamma, (void*)&beta, (void*)&wq,
                  (void*)&bq, (void*)&wk,    (void*)&bk,   (void*)&wv,
                  (void*)&bv, (void*)&wp,    (void*)&bp,   (void*)&out,
                  (void*)&ws};
  hipLaunchCooperativeKernel((const void*)fused_all, dim3(512), dim3(256),
                             args, 0, stream);
}

// Round 7
// 192.397 us; speedup vs baseline: 3.5644x; 3.5644x over previous
//
#include <hip/hip_runtime.h>
#include <hip/hip_bf16.h>

// Problem constants (B=4, C=256, H=W=64, N=4096, G=32, DQK=32)
#define NB 4
#define CD 256
#define NT 4096
#define DQ 32

typedef __attribute__((ext_vector_type(8))) __bf16 bf16x8;
typedef __attribute__((ext_vector_type(16))) float float16v;
typedef __attribute__((ext_vector_type(4))) unsigned int uint4v;
typedef __attribute__((ext_vector_type(2))) unsigned int uint2v;

#if __has_builtin(__builtin_amdgcn_exp2f)
#define EXP2(x) __builtin_amdgcn_exp2f(x)
#else
#define EXP2(x) exp2f(x)
#endif

__device__ inline unsigned short f2bf(float f) {
  unsigned u = __float_as_uint(f);
  u += 0x7fffu + ((u >> 16) & 1u);
  return (unsigned short)(u >> 16);
}

// ---------------------------------------------------------------------------
// Prep: GroupNorm partial sums (blocks 0..511, slot writes) + weight packing
// (blocks 512..1089). scale2 = log2(e)/sqrt(32) folded into wq/bq.
// ---------------------------------------------------------------------------
__global__ __launch_bounds__(256) void gn_prep(
    const float* __restrict__ x, float* __restrict__ accum,
    const float* __restrict__ wq, const float* __restrict__ wk,
    const float* __restrict__ wv, const float* __restrict__ wp,
    const float* __restrict__ bq, const float* __restrict__ bk,
    const float* __restrict__ bv, unsigned short* __restrict__ wqkv,
    unsigned short* __restrict__ wpb, float* __restrict__ bias) {
  int bx = blockIdx.x;
  int tid = threadIdx.x;
  if (bx < 512) {
    int bg = bx >> 2, ch = bx & 3;
    const float4* xp = (const float4*)(x + (size_t)bg * 32768 + ch * 8192);
    float s = 0.f, ss = 0.f;
#pragma unroll
    for (int i = 0; i < 8; i++) {
      float4 v = xp[tid + 256 * i];
      s += v.x + v.y + v.z + v.w;
      ss += v.x * v.x + v.y * v.y + v.z * v.z + v.w * v.w;
    }
    int wid = tid >> 6, lane = tid & 63;
#pragma unroll
    for (int off = 32; off >= 1; off >>= 1) {
      s += __shfl_xor(s, off);
      ss += __shfl_xor(ss, off);
    }
    __shared__ float red[8];
    if (lane == 0) { red[wid] = s; red[4 + wid] = ss; }
    __syncthreads();
    if (tid == 0) {
      accum[2 * bx] = red[0] + red[1] + red[2] + red[3];
      accum[2 * bx + 1] = red[4] + red[5] + red[6] + red[7];
    }
  } else {
    const float scale2 = 0.2550348909867343f;  // log2(e)/sqrt(32)
    int i = (bx - 512) * 256 + tid;
    if (i < 320 * 256) {
      int j = i >> 8, c = i & 255;
      float v;
      if (j < 32) v = wq[j * 256 + c] * scale2;
      else if (j < 64) v = wk[(j - 32) * 256 + c];
      else v = wv[(j - 64) * 256 + c];
      wqkv[i] = f2bf(v);
    } else if (i < 320 * 256 + 256 * 256) {
      int k = i - 320 * 256;
      wpb[k] = f2bf(wp[k]);
    } else if (i < 320 * 256 + 256 * 256 + 320) {
      int j = i - (320 * 256 + 256 * 256);
      float v;
      if (j < 32) v = bq[j] * scale2;
      else if (j < 64) v = bk[j - 32];
      else v = bv[j - 64];
      bias[j] = v;
    }
  }
}

// ---------------------------------------------------------------------------
// GroupNorm apply; combines the 4 chunk partials, writes h[B][N][C] bf16.
// ---------------------------------------------------------------------------
__global__ __launch_bounds__(256) void gn_apply(
    const float* __restrict__ x, const float* __restrict__ gamma,
    const float* __restrict__ beta, const float* __restrict__ accum,
    unsigned short* __restrict__ h) {
  int bg = blockIdx.x >> 2, nc = blockIdx.x & 3;
  int tid = threadIdx.x;
  float S = accum[8 * bg] + accum[8 * bg + 2] + accum[8 * bg + 4] +
            accum[8 * bg + 6];
  float SS = accum[8 * bg + 1] + accum[8 * bg + 3] + accum[8 * bg + 5] +
             accum[8 * bg + 7];
  float mu = S * (1.f / 32768.f);
  float var = SS * (1.f / 32768.f) - mu * mu;
  float rstd = rsqrtf(var + 1e-5f);
  int b = bg >> 5, g = bg & 31, c0 = g * 8;
  float gam[8], bet[8];
#pragma unroll
  for (int j = 0; j < 8; j++) { gam[j] = gamma[c0 + j]; bet[j] = beta[c0 + j]; }
  const float* xb = x + (size_t)bg * 32768;
#pragma unroll
  for (int i = 0; i < 4; i++) {
    int n = nc * 1024 + tid + 256 * i;
    unsigned short hv[8];
#pragma unroll
    for (int j = 0; j < 8; j++) {
      float y = (xb[j * NT + n] - mu) * rstd * gam[j] + bet[j];
      hv[j] = f2bf(y);
    }
    *(uint4v*)(h + ((size_t)(b * NT + n) * CD + c0)) = *(uint4v*)hv;
  }
}

// ---------------------------------------------------------------------------
// QKV GEMM — zero LDS, zero barriers (unchanged from R5).
// ---------------------------------------------------------------------------
__global__ __launch_bounds__(256) void qkv_gemm(
    const unsigned short* __restrict__ A, const unsigned short* __restrict__ H,
    const float* __restrict__ bias, unsigned short* __restrict__ qk,
    unsigned short* __restrict__ v) {
  int nt = blockIdx.x, mt = blockIdx.y, b = blockIdx.z;
  int tid = threadIdx.x, lane = tid & 63;
  int w = tid >> 6, mi = w & 1, ni = w >> 1;
  int l31 = lane & 31, hh = lane >> 5;
  int m_base = mt * 64 + 32 * mi;
  int n_base = nt * 128 + 64 * ni;
  const unsigned short* Arow = A + (size_t)(m_base + l31) * 256 + 8 * hh;
  const unsigned short* Hb = H + (size_t)b * NT * CD;
  const unsigned short* h0 = Hb + (size_t)(n_base + l31) * CD + 8 * hh;
  const unsigned short* h1 = h0 + (size_t)32 * CD;
  float16v acc0, acc1;
#pragma unroll
  for (int r = 0; r < 16; r++) { acc0[r] = 0.f; acc1[r] = 0.f; }
#pragma unroll
  for (int s = 0; s < 16; s++) {
    bf16x8 af = *(const bf16x8*)(Arow + 16 * s);
    bf16x8 b0 = *(const bf16x8*)(h0 + 16 * s);
    bf16x8 b1 = *(const bf16x8*)(h1 + 16 * s);
    acc0 = __builtin_amdgcn_mfma_f32_32x32x16_bf16(af, b0, acc0, 0, 0, 0);
    acc1 = __builtin_amdgcn_mfma_f32_32x32x16_bf16(af, b1, acc1, 0, 0, 0);
  }
  float bj[16];
  int jr[16];
#pragma unroll
  for (int r = 0; r < 16; r++) {
    jr[r] = m_base + (r & 3) + 8 * (r >> 2) + 4 * hh;
    bj[r] = bias[jr[r]];
  }
#pragma unroll
  for (int half = 0; half < 2; half++) {
    int n = n_base + 32 * half + l31;
#pragma unroll
    for (int r = 0; r < 16; r++) {
      float val = (half ? acc1[r] : acc0[r]) + bj[r];
      int j = jr[r];
      if (j < 64) {
        qk[((size_t)b * NT + n) * 64 + j] = f2bf(val);
      } else {
        v[((size_t)b * CD + (j - 64)) * NT + n] = f2bf(val);
      }
    }
  }
}

// ---------------------------------------------------------------------------
// Fused attention, 512-thread blocks sharing S across the full e=256 range.
// 8 waves = 2(qi) x 2(kj) x 2(eo). Waves eo=0 compute the S^T quadrant for
// keys [32kj,32kj+32) x q-rows [32qi,32qi+32), apply exp2 (log2e folded into
// q), pack bf16 into shared Pbuf; all 8 waves then do PV on 2 e-tiles each
// (e-tile = 4eo+2kj+et). This removes the R5 E0-duplicate S/exp work.
// Key-split x2 (kh): unnormalized partials to Pa/Pb + l partials to lp4;
// proj combines. Grid (128, NB) = 512 blocks; LDS 48.1 KB.
// ---------------------------------------------------------------------------
__global__ __launch_bounds__(512, 4) void attn_fused(
    const unsigned short* __restrict__ qk, const unsigned short* __restrict__ V,
    unsigned short* __restrict__ Pa, unsigned short* __restrict__ Pb,
    float* __restrict__ lp4) {
  int bx = blockIdx.x;
  int n0 = (bx >> 1) * 64;  // q-tile base
  int kh = bx & 1;          // key half
  int b = blockIdx.y;
  int tid = threadIdx.x, lane = tid & 63, w = tid >> 6;
  int qi = w & 1, kj = (w >> 1) & 1, eo = w >> 2;
  int l31 = lane & 31, hh = lane >> 5;

  __shared__ unsigned short Ks[64 * 36];        // 64 keys x 32 d (+4 pad)
  __shared__ unsigned short Vs[256 * 68];       // 256 e x 64 m (+4 pad)
  __shared__ unsigned short Pbuf[2 * 32 * 68];  // [qi][32 q][64 keys (+4 pad)]

  const unsigned short* qkb = qk + (size_t)b * NT * 64;
  const unsigned short* Vb = V + (size_t)b * CD * NT;

  // Q fragments (B-operand: lane&31 = q-row, k = d)
  int n_g = n0 + 32 * qi + l31;
  bf16x8 qfr[2];
  qfr[0] = *(const bf16x8*)&qkb[(size_t)n_g * 64 + 8 * hh];
  qfr[1] = *(const bf16x8*)&qkb[(size_t)n_g * 64 + 8 * hh + 16];

  // staging assignments
  int se = tid >> 1, smh = (tid & 1) * 32;  // V: e-row (0..255), 32-wide m-half
  int skr = tid >> 2, skc = (tid & 3) * 8;  // K (tid<256): row, 8-wide d

  int mbase = kh * 2048;
  uint4v vreg[4];
  uint4v kreg;
  {
    const unsigned short* vp = &Vb[(size_t)se * NT + mbase + smh];
#pragma unroll
    for (int u = 0; u < 4; u++) vreg[u] = *(const uint4v*)(vp + 8 * u);
    if (tid < 256)
      kreg = *(const uint4v*)&qkb[(size_t)(mbase + skr) * 64 + 32 + skc];
  }

  float16v acc[2];
#pragma unroll
  for (int et = 0; et < 2; et++)
#pragma unroll
    for (int r = 0; r < 16; r++) acc[et][r] = 0.f;
  float lsum = 0.f;
  unsigned short* Prow = &Pbuf[(qi * 32 + l31) * 68];

  for (int it = 0; it < 32; it++) {
    // stage K(it); prefetch K(it+1)
    if (tid < 256) {
      *(uint4v*)&Ks[skr * 36 + skc] = kreg;
      if (it + 1 < 32) {
        int m1 = mbase + (it + 1) * 64;
        kreg = *(const uint4v*)&qkb[(size_t)(m1 + skr) * 64 + 32 + skc];
      }
    }
    __syncthreads();  // barrier1: Ks ready; Vs/Pbuf reads of it-1 done

    // stage V(it) (read after barrier2); prefetch V(it+1)
#pragma unroll
    for (int u = 0; u < 4; u++)
      *(uint4v*)&Vs[se * 68 + smh + 8 * u] = vreg[u];
    if (it + 1 < 32) {
      int m1 = mbase + (it + 1) * 64;
      const unsigned short* vp = &Vb[(size_t)se * NT + m1 + smh];
#pragma unroll
      for (int u = 0; u < 4; u++) vreg[u] = *(const uint4v*)(vp + 8 * u);
    }

    if (eo == 0) {
      // S^T quadrant: keys [32kj,+32) x q-rows [32qi,+32)
      float16v st;
#pragma unroll
      for (int r = 0; r < 16; r++) st[r] = 0.f;
#pragma unroll
      for (int s = 0; s < 2; s++) {
        bf16x8 af = *(const bf16x8*)&Ks[(32 * kj + l31) * 36 + 16 * s + 8 * hh];
        st = __builtin_amdgcn_mfma_f32_32x32x16_bf16(af, qfr[s], st, 0, 0, 0);
      }
      // exp2 + pack pairs + write shared P rows (key cols 32kj..32kj+31)
#pragma unroll
      for (int rq = 0; rq < 4; rq++) {
        float e0 = EXP2(st[4 * rq + 0]);
        float e1 = EXP2(st[4 * rq + 1]);
        float e2 = EXP2(st[4 * rq + 2]);
        float e3 = EXP2(st[4 * rq + 3]);
        lsum += (e0 + e1) + (e2 + e3);
        uint2v pw;
        pw[0] = __builtin_amdgcn_perm(__float_as_uint(e1), __float_as_uint(e0),
                                      0x07060302u);
        pw[1] = __builtin_amdgcn_perm(__float_as_uint(e3), __float_as_uint(e2),
                                      0x07060302u);
        *(uint2v*)&Prow[8 * rq + 4 * hh + 32 * kj] = pw;
      }
    }
    __syncthreads();  // barrier2: Pbuf + Vs ready

    // PV: all 8 waves, 2 e-tiles each (e-tile = 4*eo + 2*kj + et)
#pragma unroll
    for (int sp = 0; sp < 4; sp++) {
      bf16x8 afr =
          *(const bf16x8*)&Pbuf[(qi * 32 + l31) * 68 + 16 * sp + 8 * hh];
#pragma unroll
      for (int et = 0; et < 2; et++) {
        int etile = 4 * eo + 2 * kj + et;
        bf16x8 bfr =
            *(const bf16x8*)&Vs[(32 * etile + l31) * 68 + 16 * sp + 8 * hh];
        acc[et] =
            __builtin_amdgcn_mfma_f32_32x32x16_bf16(afr, bfr, acc[et], 0, 0, 0);
      }
    }
  }

  // l partials: wave (qi,kj,eo=0) holds keys 32kj range; combine hh halves
  if (eo == 0) {
    lsum += __shfl_xor(lsum, 32);
    if (hh == 0) {
      lp4[(size_t)((kh * 2 + kj) * NB + b) * NT + n0 + 32 * qi + l31] = lsum;
    }
  }
  // unnormalized partial O
  unsigned short* Pout = (kh ? Pb : Pa) + (size_t)b * NT * CD;
#pragma unroll
  for (int r = 0; r < 16; r++) {
    int nl = (r & 3) + 8 * (r >> 2) + 4 * hh;
    size_t row = (size_t)(n0 + 32 * qi + nl) * CD + l31;
#pragma unroll
    for (int et = 0; et < 2; et++) {
      int etile = 4 * eo + 2 * kj + et;
      Pout[row + 32 * etile] = f2bf(acc[et][r]);
    }
  }
}

// ---------------------------------------------------------------------------
// Proj GEMM + partial-combine + bias + residual (unchanged from R5).
// ---------------------------------------------------------------------------
__device__ inline bf16x8 combine_frag(const unsigned short* p0,
                                      const unsigned short* p1, float inv) {
  uint4v ua = *(const uint4v*)p0;
  uint4v ub = *(const uint4v*)p1;
  uint4v r;
#pragma unroll
  for (int j = 0; j < 4; j++) {
    float lo = __uint_as_float(ua[j] << 16) + __uint_as_float(ub[j] << 16);
    float hi = __uint_as_float(ua[j] & 0xffff0000u) +
               __uint_as_float(ub[j] & 0xffff0000u);
    lo *= inv;
    hi *= inv;
    r[j] = __builtin_amdgcn_perm(__float_as_uint(hi), __float_as_uint(lo),
                                 0x07060302u);
  }
  return *(bf16x8*)&r;
}

__global__ __launch_bounds__(256) void proj_gemm(
    const unsigned short* __restrict__ Wp, const unsigned short* __restrict__ Pa,
    const unsigned short* __restrict__ Pb, const float* __restrict__ lp4,
    const float* __restrict__ bp, const float* __restrict__ x,
    float* __restrict__ out) {
  int nt = blockIdx.x, mt = blockIdx.y, b = blockIdx.z;
  int tid = threadIdx.x, lane = tid & 63;
  int w = tid >> 6, mi = w & 1, ni = w >> 1;
  int l31 = lane & 31, hh = lane >> 5;
  int m_base = mt * 64 + 32 * mi;
  int n_base = nt * 128 + 64 * ni;
  const unsigned short* Arow = Wp + (size_t)(m_base + l31) * 256 + 8 * hh;
  int nA = n_base + l31, nB = nA + 32;
  float lA = 0.f, lB = 0.f;
#pragma unroll
  for (int s4 = 0; s4 < 4; s4++) {
    lA += lp4[(size_t)(s4 * NB + b) * NT + nA];
    lB += lp4[(size_t)(s4 * NB + b) * NT + nB];
  }
  float invA = 1.f / lA, invB = 1.f / lB;
  const unsigned short* a0 = Pa + ((size_t)b * NT + nA) * CD + 8 * hh;
  const unsigned short* a1 = Pa + ((size_t)b * NT + nB) * CD + 8 * hh;
  const unsigned short* c0 = Pb + ((size_t)b * NT + nA) * CD + 8 * hh;
  const unsigned short* c1 = Pb + ((size_t)b * NT + nB) * CD + 8 * hh;
  float16v acc0, acc1;
#pragma unroll
  for (int r = 0; r < 16; r++) { acc0[r] = 0.f; acc1[r] = 0.f; }
#pragma unroll
  for (int s = 0; s < 16; s++) {
    bf16x8 af = *(const bf16x8*)(Arow + 16 * s);
    bf16x8 b0 = combine_frag(a0 + 16 * s, c0 + 16 * s, invA);
    bf16x8 b1 = combine_frag(a1 + 16 * s, c1 + 16 * s, invB);
    acc0 = __builtin_amdgcn_mfma_f32_32x32x16_bf16(af, b0, acc0, 0, 0, 0);
    acc1 = __builtin_amdgcn_mfma_f32_32x32x16_bf16(af, b1, acc1, 0, 0, 0);
  }
#pragma unroll
  for (int half = 0; half < 2; half++) {
    int n = n_base + 32 * half + l31;
#pragma unroll
    for (int r = 0; r < 16; r++) {
      int f = m_base + (r & 3) + 8 * (r >> 2) + 4 * hh;
      size_t idx = ((size_t)b * CD + f) * NT + n;
      out[idx] = x[idx] + (half ? acc1[r] : acc0[r]) + bp[f];
    }
  }
}

extern "C" void kernel_launch(void* const* d_in, const int* in_sizes, int n_in,
                              void* d_out, int out_size, void* d_ws,
                              size_t ws_size, hipStream_t stream) {
  (void)in_sizes; (void)n_in; (void)out_size; (void)ws_size;
  const float* x = (const float*)d_in[0];
  const float* gamma = (const float*)d_in[1];
  const float* beta = (const float*)d_in[2];
  const float* wq = (const float*)d_in[3];
  const float* bq = (const float*)d_in[4];
  const float* wk = (const float*)d_in[5];
  const float* bk = (const float*)d_in[6];
  const float* wv = (const float*)d_in[7];
  const float* bv = (const float*)d_in[8];
  const float* wp = (const float*)d_in[9];
  const float* bp = (const float*)d_in[10];
  float* out = (float*)d_out;

  char* ws = (char*)d_ws;
  unsigned short* h_ws = (unsigned short*)ws;               // 8 MB (reused: Pa)
  unsigned short* qk_ws = (unsigned short*)(ws + 8388608);  // 2 MB
  unsigned short* v_ws = (unsigned short*)(ws + 10485760);  // 8 MB
  unsigned short* o_ws = (unsigned short*)(ws + 18874368);  // 8 MB (Pb)
  unsigned short* wqkv_b = (unsigned short*)(ws + 27262976);  // 160 KB
  unsigned short* wp_b = (unsigned short*)(ws + 27426816);    // 128 KB
  float* bias_q = (float*)(ws + 27557888);                    // 1.25 KB
  float* accum = (float*)(ws + 27559168);                     // 4 KB
  float* lp4 = (float*)(ws + 27563264);                       // 256 KB

  gn_prep<<<1090, 256, 0, stream>>>(x, accum, wq, wk, wv, wp, bq, bk, bv,
                                    wqkv_b, wp_b, bias_q);
  gn_apply<<<512, 256, 0, stream>>>(x, gamma, beta, accum, h_ws);
  dim3 gq(32, 5, NB);
  qkv_gemm<<<gq, 256, 0, stream>>>(wqkv_b, h_ws, bias_q, qk_ws, v_ws);
  dim3 ga(128, NB);
  attn_fused<<<ga, 512, 0, stream>>>(qk_ws, v_ws, h_ws, o_ws, lp4);
  dim3 gp(32, 4, NB);
  proj_gemm<<<gp, 256, 0, stream>>>(wp_b, h_ws, o_ws, lp4, bp, x, out);
}